// Round 19
// baseline (134.395 us; speedup 1.0000x reference)
//
#include <hip/hip_runtime.h>
#include <math.h>

#define N_POINTS 32768
#define NUM_EMBED 8192
#define CH 64                                // chunks (fits 64-bit survivor mask)
#define CPC (NUM_EMBED / CH)                 // 128 candidates per chunk
#define CSTRIDE 4096                         // 64*64, channel stride in z [B,C,H,W]

// order-preserving bijection float -> uint32 (total order == float <)
__device__ __forceinline__ unsigned int fkey(float f) {
    unsigned int b = __float_as_uint(f);
    return b ^ (0x80000000u | (unsigned int)((int)b >> 31));
}

// ---------------- kernel A (fused filter+resolve): block = 4 waves = 16 points.
// Stage 1 (exact-chain dot-max): wave owns 4 points; lane = (point wid*4+(lane>>4),
// cand-slot lane&15). Per chunk: 8 coalesced float4 E loads, dot = mul + ascending-fma
// (bit-identical to the reference chain), running fmax; 4x shfl_xor folds the 16-lane
// group -> chunk-max -> padded LDS sCm[64][17].
// Stage 2 (r9-r18 proven resolve): shfl gmax; threshold = gmax - (2u + 1e-7) [r9 window];
// ballot survivors; coalesced EXACT-chain rescan; 64-bit key min = first-index argmin.
__global__ __launch_bounds__(256) void vq_fused_kernel(
        const float* __restrict__ z, const float4* __restrict__ E,
        float* __restrict__ out, double* __restrict__ partial) {
    __shared__ float sCm[CH][17];                // 4.3 KB, odd stride: conflict-free
    __shared__ double sLoss[16];
    const int lane = threadIdx.x & 63;
    const int wid = threadIdx.x >> 6;
    const int n0 = blockIdx.x * 16;
    const int cs = lane & 15;                    // candidate slot
    const int pt = wid * 4 + (lane >> 4);        // this lane's point (0..15)

    // ---- this lane's point components (strided loads, L2-resident)
    float z0, z1, z2, z3;
    {
        int n = n0 + pt;
        int b = n >> 12, hw = n & 4095;
        const float* zp = z + b * 16384 + hw;
        z0 = zp[0];
        z1 = zp[CSTRIDE];
        z2 = zp[2 * CSTRIDE];
        z3 = zp[3 * CSTRIDE];
    }

    // ---- stage 1: 64 chunks; per chunk 8 iters x 16 cands
    for (int c = 0; c < CH; ++c) {
        float rm = -__builtin_inff();
        #pragma unroll
        for (int t = 0; t < 8; ++t) {
            float4 e = E[c * CPC + t * 16 + cs];   // coalesced 256B/wave, group-broadcast
            float dot = __fmul_rn(z0, e.x);        // exact reference chain bits
            dot = __fmaf_rn(z1, e.y, dot);
            dot = __fmaf_rn(z2, e.z, dot);
            dot = __fmaf_rn(z3, e.w, dot);
            rm = fmaxf(rm, dot);
        }
        // fold the 16-lane candidate group (exact selection)
        rm = fmaxf(rm, __shfl_xor(rm, 1));
        rm = fmaxf(rm, __shfl_xor(rm, 2));
        rm = fmaxf(rm, __shfl_xor(rm, 4));
        rm = fmaxf(rm, __shfl_xor(rm, 8));
        if (cs == 0) sCm[c][pt] = rm;
    }
    __syncthreads();

    // ---- stage 2: wave wid resolves points wid*4 .. wid*4+3
    for (int q = 0; q < 4; ++q) {
        int pl = wid * 4 + q;
        int n = n0 + pl;
        int b = n >> 12, hw = n & 4095;
        const float* zp = z + b * 16384 + hw;      // wave-uniform broadcast loads
        float y0 = zp[0];
        float y1 = zp[CSTRIDE];
        float y2 = zp[2 * CSTRIDE];
        float y3 = zp[3 * CSTRIDE];
        float zz = __fmul_rn(y0, y0);
        zz = __fadd_rn(zz, __fmul_rn(y1, y1));
        zz = __fadd_rn(zz, __fmul_rn(y2, y2));
        zz = __fadd_rn(zz, __fmul_rn(y3, y3));

        float cm = sCm[lane][pl];                  // lane = chunk; stride 17: conflict-free
        float gmax = cm;
        #pragma unroll
        for (int off = 32; off; off >>= 1)
            gmax = fmaxf(gmax, __shfl_xor(gmax, off));

        // conservative bound (r9-proven): survivors have dot >= gmax - (2u + 1e-7)
        float u = __fmul_rn(__fadd_rn(zz, 0.01f), 2.38418579e-07f);
        float thr = __fsub_rn(gmax, __fadd_rn(__fadd_rn(u, u), 1e-7f));
        unsigned long long mask = __ballot(cm >= thr);   // wave-uniform, >=1 bit set

        unsigned long long bkey = ~0ull;
        while (mask) {
            int c = __builtin_ctzll(mask);
            mask &= mask - 1ull;
            int j0 = c * CPC + lane;
            #pragma unroll
            for (int h = 0; h < 2; ++h) {
                int j = j0 + h * 64;
                float4 e = E[j];
                float ee = __fmul_rn(e.x, e.x);
                ee = __fadd_rn(ee, __fmul_rn(e.y, e.y));
                ee = __fadd_rn(ee, __fmul_rn(e.z, e.z));
                ee = __fadd_rn(ee, __fmul_rn(e.w, e.w));
                float dot = __fmul_rn(y0, e.x);
                dot = __fmaf_rn(y1, e.y, dot);
                dot = __fmaf_rn(y2, e.z, dot);
                dot = __fmaf_rn(y3, e.w, dot);
                float d = __fmaf_rn(-2.0f, dot, __fadd_rn(zz, ee));
                unsigned long long key =
                    ((unsigned long long)fkey(d) << 32) | (unsigned int)j;
                bkey = key < bkey ? key : bkey;
            }
        }
        #pragma unroll
        for (int off = 32; off; off >>= 1) {
            unsigned long long o = __shfl_xor(bkey, off);
            bkey = o < bkey ? o : bkey;
        }
        int besti = (int)(unsigned int)(bkey & 0xFFFFFFFFull);

        if (lane == 0) {
            float4 e = E[besti];
            float* op = out + b * 16384 + hw;
            float t0 = __fsub_rn(e.x, y0);
            float t1 = __fsub_rn(e.y, y1);
            float t2 = __fsub_rn(e.z, y2);
            float t3 = __fsub_rn(e.w, y3);
            op[0]           = __fadd_rn(y0, t0); // straight-through: z + (z_q - z)
            op[CSTRIDE]     = __fadd_rn(y1, t1);
            op[2 * CSTRIDE] = __fadd_rn(y2, t2);
            op[3 * CSTRIDE] = __fadd_rn(y3, t3);
            out[131073 + n] = (float)besti;      // indices as float32 (exact)
            sLoss[pl] = (double)__fmul_rn(t0, t0) + (double)__fmul_rn(t1, t1)
                      + (double)__fmul_rn(t2, t2) + (double)__fmul_rn(t3, t3);
        }
    }
    __syncthreads();
    if (threadIdx.x == 0) {
        double s = 0.0;
        #pragma unroll
        for (int w = 0; w < 16; ++w) s += sLoss[w];
        partial[blockIdx.x] = s;
    }
}

// ---------------- kernel B: deterministic loss reduce (2048 partials)
__global__ void vq_loss_kernel(const double* __restrict__ partial, float* __restrict__ out) {
    __shared__ double sdata[256];
    int t = threadIdx.x;
    double s = 0.0;
    for (int i = t; i < 2048; i += 256) s += partial[i];
    sdata[t] = s;
    __syncthreads();
    #pragma unroll
    for (int st = 128; st > 0; st >>= 1) {
        if (t < st) sdata[t] += sdata[t + st];
        __syncthreads();
    }
    if (t == 0) {
        float m = (float)(sdata[0] / 131072.0);
        // loss = mean + BETA*mean (both means are numerically identical)
        out[131072] = __fadd_rn(m, __fmul_rn(0.25f, m));
    }
}

extern "C" void kernel_launch(void* const* d_in, const int* in_sizes, int n_in,
                              void* d_out, int out_size, void* d_ws, size_t ws_size,
                              hipStream_t stream) {
    const float* z = (const float*)d_in[0];
    const float4* E = (const float4*)d_in[1];
    float* out = (float*)d_out;

    double* partial = (double*)d_ws;                          // 16 KB

    vq_fused_kernel<<<N_POINTS / 16, 256, 0, stream>>>(z, E, out, partial);
    vq_loss_kernel<<<1, 256, 0, stream>>>(partial, out);
}

// Round 20
// 83.531 us; speedup vs baseline: 1.6089x; 1.6089x over previous
//
#include <hip/hip_runtime.h>
#include <math.h>

#define N_POINTS 32768
#define NUM_EMBED 8192
#define CH 64                                // chunks (fits 64-bit survivor mask)
#define CPC (NUM_EMBED / CH)                 // 128 candidates per chunk
#define GRP 8                                // chunks staged per group (16 KB)
#define CSTRIDE 4096                         // 64*64, channel stride in z [B,C,H,W]

// order-preserving bijection float -> uint32 (total order == float <)
__device__ __forceinline__ unsigned int fkey(float f) {
    unsigned int b = __float_as_uint(f);
    return b ^ (0x80000000u | (unsigned int)((int)b >> 31));
}

// ---------------- kernel A (fused filter+resolve): block = 4 waves = 16 points.
// Stage 1 (r9-style LDS-staged exact-chain dot-max): loop 8 groups of 8 chunks;
// cooperative 16KB stage -> barrier -> per chunk 8x ds_read_b128 (broadcast, <=2-way)
// + dot (mul + ascending fma, bit-identical to reference chain) + fmax; shfl-fold
// the 16-lane candidate group -> sCm[64][17].
// Stage 2 (r9-r18 proven resolve): shfl gmax; thr = gmax - (2u + 1e-7) [r9 window];
// ballot survivors; coalesced EXACT-chain rescan; 64-bit key min = first-index argmin.
__global__ __launch_bounds__(256) void vq_fused_kernel(
        const float* __restrict__ z, const float4* __restrict__ E,
        float* __restrict__ out, double* __restrict__ partial) {
    __shared__ alignas(16) float4 sE4[GRP * CPC];   // 16 KB: 8 chunks of candidates
    __shared__ float sCm[CH][17];                   // 4.3 KB, odd stride: conflict-free
    __shared__ double sLoss[16];
    const int lane = threadIdx.x & 63;
    const int wid = threadIdx.x >> 6;
    const int n0 = blockIdx.x * 16;
    const int cs = lane & 15;                    // candidate slot
    const int pt = wid * 4 + (lane >> 4);        // this lane's point (0..15)

    // ---- this lane's point components (strided loads, L2-resident)
    float z0, z1, z2, z3;
    {
        int n = n0 + pt;
        int b = n >> 12, hw = n & 4095;
        const float* zp = z + b * 16384 + hw;
        z0 = zp[0];
        z1 = zp[CSTRIDE];
        z2 = zp[2 * CSTRIDE];
        z3 = zp[3 * CSTRIDE];
    }

    // ---- stage 1: 8 groups x (stage 8 chunks -> compute)
    for (int g = 0; g < 8; ++g) {
        if (g) __syncthreads();                  // prior group's reads done
        #pragma unroll
        for (int i = 0; i < 4; ++i)              // 1024 float4, coalesced
            sE4[threadIdx.x + i * 256] = E[g * (GRP * CPC) + threadIdx.x + i * 256];
        __syncthreads();

        #pragma unroll
        for (int cc = 0; cc < GRP; ++cc) {
            float rm = -__builtin_inff();
            #pragma unroll
            for (int t = 0; t < 8; ++t) {
                float4 e = sE4[cc * CPC + t * 16 + cs];   // broadcast ds_read_b128
                float dot = __fmul_rn(z0, e.x);           // exact reference chain bits
                dot = __fmaf_rn(z1, e.y, dot);
                dot = __fmaf_rn(z2, e.z, dot);
                dot = __fmaf_rn(z3, e.w, dot);
                rm = fmaxf(rm, dot);
            }
            // fold the 16-lane candidate group (exact selection)
            rm = fmaxf(rm, __shfl_xor(rm, 1));
            rm = fmaxf(rm, __shfl_xor(rm, 2));
            rm = fmaxf(rm, __shfl_xor(rm, 4));
            rm = fmaxf(rm, __shfl_xor(rm, 8));
            if (cs == 0) sCm[g * GRP + cc][pt] = rm;
        }
    }
    __syncthreads();

    // ---- stage 2: wave wid resolves points wid*4 .. wid*4+3
    for (int q = 0; q < 4; ++q) {
        int pl = wid * 4 + q;
        int n = n0 + pl;
        int b = n >> 12, hw = n & 4095;
        const float* zp = z + b * 16384 + hw;      // wave-uniform broadcast loads
        float y0 = zp[0];
        float y1 = zp[CSTRIDE];
        float y2 = zp[2 * CSTRIDE];
        float y3 = zp[3 * CSTRIDE];
        float zz = __fmul_rn(y0, y0);
        zz = __fadd_rn(zz, __fmul_rn(y1, y1));
        zz = __fadd_rn(zz, __fmul_rn(y2, y2));
        zz = __fadd_rn(zz, __fmul_rn(y3, y3));

        float cm = sCm[lane][pl];                  // lane = chunk; stride 17: conflict-free
        float gmax = cm;
        #pragma unroll
        for (int off = 32; off; off >>= 1)
            gmax = fmaxf(gmax, __shfl_xor(gmax, off));

        // conservative bound (r9-proven): survivors have dot >= gmax - (2u + 1e-7)
        float u = __fmul_rn(__fadd_rn(zz, 0.01f), 2.38418579e-07f);
        float thr = __fsub_rn(gmax, __fadd_rn(__fadd_rn(u, u), 1e-7f));
        unsigned long long mask = __ballot(cm >= thr);   // wave-uniform, >=1 bit set

        unsigned long long bkey = ~0ull;
        while (mask) {
            int c = __builtin_ctzll(mask);
            mask &= mask - 1ull;
            int j0 = c * CPC + lane;
            #pragma unroll
            for (int h = 0; h < 2; ++h) {
                int j = j0 + h * 64;
                float4 e = E[j];
                float ee = __fmul_rn(e.x, e.x);
                ee = __fadd_rn(ee, __fmul_rn(e.y, e.y));
                ee = __fadd_rn(ee, __fmul_rn(e.z, e.z));
                ee = __fadd_rn(ee, __fmul_rn(e.w, e.w));
                float dot = __fmul_rn(y0, e.x);
                dot = __fmaf_rn(y1, e.y, dot);
                dot = __fmaf_rn(y2, e.z, dot);
                dot = __fmaf_rn(y3, e.w, dot);
                float d = __fmaf_rn(-2.0f, dot, __fadd_rn(zz, ee));
                unsigned long long key =
                    ((unsigned long long)fkey(d) << 32) | (unsigned int)j;
                bkey = key < bkey ? key : bkey;
            }
        }
        #pragma unroll
        for (int off = 32; off; off >>= 1) {
            unsigned long long o = __shfl_xor(bkey, off);
            bkey = o < bkey ? o : bkey;
        }
        int besti = (int)(unsigned int)(bkey & 0xFFFFFFFFull);

        if (lane == 0) {
            float4 e = E[besti];
            float* op = out + b * 16384 + hw;
            float t0 = __fsub_rn(e.x, y0);
            float t1 = __fsub_rn(e.y, y1);
            float t2 = __fsub_rn(e.z, y2);
            float t3 = __fsub_rn(e.w, y3);
            op[0]           = __fadd_rn(y0, t0); // straight-through: z + (z_q - z)
            op[CSTRIDE]     = __fadd_rn(y1, t1);
            op[2 * CSTRIDE] = __fadd_rn(y2, t2);
            op[3 * CSTRIDE] = __fadd_rn(y3, t3);
            out[131073 + n] = (float)besti;      // indices as float32 (exact)
            sLoss[pl] = (double)__fmul_rn(t0, t0) + (double)__fmul_rn(t1, t1)
                      + (double)__fmul_rn(t2, t2) + (double)__fmul_rn(t3, t3);
        }
    }
    __syncthreads();
    if (threadIdx.x == 0) {
        double s = 0.0;
        #pragma unroll
        for (int w = 0; w < 16; ++w) s += sLoss[w];
        partial[blockIdx.x] = s;
    }
}

// ---------------- kernel B: deterministic loss reduce (2048 partials)
__global__ void vq_loss_kernel(const double* __restrict__ partial, float* __restrict__ out) {
    __shared__ double sdata[256];
    int t = threadIdx.x;
    double s = 0.0;
    for (int i = t; i < 2048; i += 256) s += partial[i];
    sdata[t] = s;
    __syncthreads();
    #pragma unroll
    for (int st = 128; st > 0; st >>= 1) {
        if (t < st) sdata[t] += sdata[t + st];
        __syncthreads();
    }
    if (t == 0) {
        float m = (float)(sdata[0] / 131072.0);
        // loss = mean + BETA*mean (both means are numerically identical)
        out[131072] = __fadd_rn(m, __fmul_rn(0.25f, m));
    }
}

extern "C" void kernel_launch(void* const* d_in, const int* in_sizes, int n_in,
                              void* d_out, int out_size, void* d_ws, size_t ws_size,
                              hipStream_t stream) {
    const float* z = (const float*)d_in[0];
    const float4* E = (const float4*)d_in[1];
    float* out = (float*)d_out;

    double* partial = (double*)d_ws;                          // 16 KB

    vq_fused_kernel<<<N_POINTS / 16, 256, 0, stream>>>(z, E, out, partial);
    vq_loss_kernel<<<1, 256, 0, stream>>>(partial, out);
}

// Round 21
// 53.056 us; speedup vs baseline: 2.5331x; 1.5744x over previous
//
#include <hip/hip_runtime.h>
#include <math.h>

typedef float v2f __attribute__((ext_vector_type(2)));

#define N_POINTS 32768
#define NUM_EMBED 8192
#define NPAIRS 4096
#define CH 64                                // chunks (fits 64-bit survivor mask)
#define CPC (NUM_EMBED / CH)                 // 128 candidates per chunk
#define PAIRS (NPAIRS / CH)                  // 64 pairs per chunk
#define PPT 8                                // filter points per thread (r9-measured shape)
#define RB 1024                              // resolve block threads (16 waves, 16 points)
#define RPB (RB / 64)                        // 16 points per resolve block
#define CSTRIDE 4096                         // 64*64, channel stride in z [B,C,H,W]

// ---------------- kernel A: build pair-interleaved codebook (bits preserved)
__global__ void vq_prep_kernel(const float4* __restrict__ E, v2f* __restrict__ Epk) {
    int p = blockIdx.x * 256 + threadIdx.x;
    if (p < NPAIRS) {
        float4 a = E[2 * p];
        float4 b = E[2 * p + 1];
        Epk[4 * p + 0] = (v2f){a.x, b.x};
        Epk[4 * p + 1] = (v2f){a.y, b.y};
        Epk[4 * p + 2] = (v2f){a.z, b.z};
        Epk[4 * p + 3] = (v2f){a.w, b.w};
    }
}

// packed f32 ops forced via inline asm (per-half IEEE rn, bit-identical to scalar chain)
__device__ __forceinline__ v2f pk_mul(v2f a, v2f b) {
    v2f d; asm("v_pk_mul_f32 %0, %1, %2" : "=v"(d) : "v"(a), "v"(b)); return d;
}
__device__ __forceinline__ v2f pk_fma(v2f a, v2f b, v2f c) {
    v2f d; asm("v_pk_fma_f32 %0, %1, %2, %3" : "=v"(d) : "v"(a), "v"(b), "v"(c)); return d;
}

// order-preserving bijection float -> uint32 (total order == float <)
__device__ __forceinline__ unsigned int fkey(float f) {
    unsigned int b = __float_as_uint(f);
    return b ^ (0x80000000u | (unsigned int)((int)b >> 31));
}

// ---------------- kernel B (filter): per (point, chunk) max of dot_j (r9-measured ~17us)
// dot chain = exact XLA chain bits (mul + ascending fma) -> fmax selection is exact.
// Wave-uniform LDS reads: one b128 serves 64 lanes x 8 points (LDS ~10us < VALU floor).
__global__ __launch_bounds__(256) void vq_filter_kernel(
        const float* __restrict__ z, const v2f* __restrict__ Epk,
        float* __restrict__ cmax) {
    __shared__ alignas(16) v2f sE[PAIRS * 4];   // 2 KB

    const int c = blockIdx.y;
    if (threadIdx.x < PAIRS * 2) {
        ((float4*)sE)[threadIdx.x] =
            ((const float4*)(Epk + (size_t)c * PAIRS * 4))[threadIdx.x];
    }

    const int n0 = blockIdx.x * (256 * PPT) + threadIdx.x;

    v2f zv[PPT][4];
    #pragma unroll
    for (int p = 0; p < PPT; ++p) {
        int n = n0 + p * 256;
        int b = n >> 12, hw = n & 4095;
        const float* zp = z + b * 16384 + hw;
        zv[p][0] = (v2f){zp[0], zp[0]};
        zv[p][1] = (v2f){zp[CSTRIDE], zp[CSTRIDE]};
        zv[p][2] = (v2f){zp[2 * CSTRIDE], zp[2 * CSTRIDE]};
        zv[p][3] = (v2f){zp[3 * CSTRIDE], zp[3 * CSTRIDE]};
    }

    __syncthreads();

    float run[PPT];
    #pragma unroll
    for (int p = 0; p < PPT; ++p) run[p] = -__builtin_inff();

    const float4* sE4 = (const float4*)sE;
    #pragma unroll 2
    for (int t = 0; t < PAIRS; ++t) {
        // uniform LDS reads -> hardware broadcast, no bank conflicts
        float4 E01 = sE4[2 * t];       // {e0.lo,e0.hi, e1.lo,e1.hi}
        float4 E23 = sE4[2 * t + 1];   // {e2.lo,e2.hi, e3.lo,e3.hi}
        v2f e0 = {E01.x, E01.y};
        v2f e1 = {E01.z, E01.w};
        v2f e2 = {E23.x, E23.y};
        v2f e3 = {E23.z, E23.w};
        #pragma unroll
        for (int p = 0; p < PPT; ++p) {
            v2f dot = pk_mul(zv[p][0], e0);       // z0*e0       (rn)
            dot = pk_fma(zv[p][1], e1, dot);      // ascending-k fma chain
            dot = pk_fma(zv[p][2], e2, dot);
            dot = pk_fma(zv[p][3], e3, dot);
            run[p] = fmaxf(fmaxf(dot.x, dot.y), run[p]);  // exact selection (v_max3)
        }
    }

    #pragma unroll
    for (int p = 0; p < PPT; ++p)
        cmax[(size_t)c * N_POINTS + n0 + p * 256] = run[p];   // coalesced 256B/wave
}

// ---------------- kernel C (resolve): 16 waves / 16 points per block (r16-proven).
// Phase 1: 1024 threads load the block's [64c][16n] cmax tile as FULL 64B lines
// (thread t -> row t>>4, col t&15) into padded LDS. Phase 2 per wave (r11-proven):
// shfl-reduce gmax; conservative threshold; ballot -> survivor mask; coalesced
// exact rescan of survivors; 64-bit key min-reduce = exact first-index argmin.
__global__ __launch_bounds__(RB) void vq_resolve_kernel(
        const float* __restrict__ z, const float4* __restrict__ E,
        const float* __restrict__ cmax,
        float* __restrict__ out, double* __restrict__ partial) {
    __shared__ float sCm[CH][RPB + 1];           // 64 x 17 floats: odd stride, <=2-way
    __shared__ double sdata[RPB];
    const int lane = threadIdx.x & 63;
    const int wid = threadIdx.x >> 6;
    const int n0 = blockIdx.x * RPB;
    const int n = n0 + wid;

    // ---- phase 1: cooperative tile load, line-granular (64B per 16 threads)
    {
        int t = threadIdx.x;
        sCm[t >> 4][t & 15] = cmax[(size_t)(t >> 4) * N_POINTS + n0 + (t & 15)];
    }

    const int b = n >> 12;
    const int hw = n & 4095;
    const float* zp = z + b * 16384 + hw;
    float z0 = zp[0];
    float z1 = zp[CSTRIDE];
    float z2 = zp[2 * CSTRIDE];
    float z3 = zp[3 * CSTRIDE];
    float zz = __fmul_rn(z0, z0);
    zz = __fadd_rn(zz, __fmul_rn(z1, z1));
    zz = __fadd_rn(zz, __fmul_rn(z2, z2));
    zz = __fadd_rn(zz, __fmul_rn(z3, z3));

    __syncthreads();

    // lane c holds chunk c's max-dot; wave max-reduce
    float cm = sCm[lane][wid];
    float gmax = cm;
    #pragma unroll
    for (int off = 32; off; off >>= 1)
        gmax = fmaxf(gmax, __shfl_xor(gmax, off));

    // conservative bound (proven round 9): survivors have dot >= gmax - (2u + 1e-7)
    float u = __fmul_rn(__fadd_rn(zz, 0.01f), 2.38418579e-07f);   // (zz+.01)*2^-22
    float thr = __fsub_rn(gmax, __fadd_rn(__fadd_rn(u, u), 1e-7f));
    unsigned long long mask = __ballot(cm >= thr);   // wave-uniform, >=1 bit set

    // exact rescan of surviving chunks (coalesced: lane -> j0+lane, j0+64+lane)
    unsigned long long bkey = ~0ull;
    while (mask) {
        int c = __builtin_ctzll(mask);
        mask &= mask - 1ull;
        int j0 = c * CPC + lane;
        #pragma unroll
        for (int h = 0; h < 2; ++h) {
            int j = j0 + h * 64;
            float4 e = E[j];
            float ee = __fmul_rn(e.x, e.x);
            ee = __fadd_rn(ee, __fmul_rn(e.y, e.y));
            ee = __fadd_rn(ee, __fmul_rn(e.z, e.z));
            ee = __fadd_rn(ee, __fmul_rn(e.w, e.w));
            float dot = __fmul_rn(z0, e.x);
            dot = __fmaf_rn(z1, e.y, dot);
            dot = __fmaf_rn(z2, e.z, dot);
            dot = __fmaf_rn(z3, e.w, dot);
            float d = __fmaf_rn(-2.0f, dot, __fadd_rn(zz, ee));
            // key: (orderable d) << 32 | j  -> min key = min d, tie -> min j (first index)
            unsigned long long key =
                ((unsigned long long)fkey(d) << 32) | (unsigned int)j;
            bkey = key < bkey ? key : bkey;
        }
    }
    #pragma unroll
    for (int off = 32; off; off >>= 1) {
        unsigned long long o = __shfl_xor(bkey, off);
        bkey = o < bkey ? o : bkey;
    }
    int besti = (int)(unsigned int)(bkey & 0xFFFFFFFFull);

    if (lane == 0) {
        float4 e = E[besti];
        float* op = out + b * 16384 + hw;
        float t0 = __fsub_rn(e.x, z0);
        float t1 = __fsub_rn(e.y, z1);
        float t2 = __fsub_rn(e.z, z2);
        float t3 = __fsub_rn(e.w, z3);
        op[0]           = __fadd_rn(z0, t0);     // straight-through: z + (z_q - z)
        op[CSTRIDE]     = __fadd_rn(z1, t1);
        op[2 * CSTRIDE] = __fadd_rn(z2, t2);
        op[3 * CSTRIDE] = __fadd_rn(z3, t3);
        out[131073 + n] = (float)besti;          // indices as float32 (exact)
        double ds = (double)__fmul_rn(t0, t0) + (double)__fmul_rn(t1, t1)
                  + (double)__fmul_rn(t2, t2) + (double)__fmul_rn(t3, t3);
        sdata[wid] = ds;
    }
    __syncthreads();
    if (threadIdx.x == 0) {
        double s = 0.0;
        #pragma unroll
        for (int w = 0; w < RPB; ++w) s += sdata[w];
        partial[blockIdx.x] = s;
    }
}

// ---------------- kernel D: deterministic loss reduce (2048 partials)
__global__ void vq_loss_kernel(const double* __restrict__ partial, float* __restrict__ out) {
    __shared__ double sdata[256];
    int t = threadIdx.x;
    double s = 0.0;
    for (int i = t; i < 2048; i += 256) s += partial[i];
    sdata[t] = s;
    __syncthreads();
    #pragma unroll
    for (int st = 128; st > 0; st >>= 1) {
        if (t < st) sdata[t] += sdata[t + st];
        __syncthreads();
    }
    if (t == 0) {
        float m = (float)(sdata[0] / 131072.0);
        // loss = mean + BETA*mean (both means are numerically identical)
        out[131072] = __fadd_rn(m, __fmul_rn(0.25f, m));
    }
}

extern "C" void kernel_launch(void* const* d_in, const int* in_sizes, int n_in,
                              void* d_out, int out_size, void* d_ws, size_t ws_size,
                              hipStream_t stream) {
    const float* z = (const float*)d_in[0];
    const float4* E = (const float4*)d_in[1];
    float* out = (float*)d_out;

    char* ws = (char*)d_ws;
    v2f* Epk = (v2f*)ws;                                      // 128 KB
    float* cmaxb = (float*)(ws + 131072);                     // 8 MB, [c][n]
    double* partial = (double*)(ws + 131072 + (size_t)CH * N_POINTS * 4);  // 16 KB

    vq_prep_kernel<<<NPAIRS / 256, 256, 0, stream>>>(E, Epk);
    vq_filter_kernel<<<dim3(N_POINTS / (256 * PPT), CH), 256, 0, stream>>>(z, Epk, cmaxb);
    vq_resolve_kernel<<<N_POINTS / RPB, RB, 0, stream>>>(z, E, cmaxb, out, partial);
    vq_loss_kernel<<<1, 256, 0, stream>>>(partial, out);
}